// Round 5
// baseline (491.388 us; speedup 1.0000x reference)
//
#include <hip/hip_runtime.h>

typedef _Float16 f16x8 __attribute__((ext_vector_type(8)));
typedef float    f32x4 __attribute__((ext_vector_type(4)));

#define NROWS  300000
#define NTILES (NROWS/16)      // 18750
#define WPB    8
#define TPB    512
#define NBLK   ((NTILES + WPB - 1) / WPB)  // 2344

// weight-lo plane stored pre-scaled by 2^11 to stay out of f16-denormal range
#define LSCALE     2048.0f
#define INV_LSCALE 4.8828125e-4f   // 2^-11, exact

// ---- LDS layout (halves). Weights n-major, hi plane at col 0, lo plane at LO offset.
#define RS64   136   // K=64 rows: hi 0..63, lo 72..135 (16B-aligned planes)
#define LO64   72
#define RS128  264   // K=128 rows: hi 0..127, lo 136..263
#define LO128  136
// phase 1 weights
#define OFF_FC1 0
#define OFF_FC2 8704
#define OFF_FC3 17408        // 256*136 -> end 52224
// phase 2 weights (same region, re-staged after barrier)
#define OFF_TP1 0
#define OFF_TP2 8704
#define OFF_TP3 17408
#define OFF_TP4 26112
#define OFF_LIN0 34816       // 64*264
#define OFF_LIN1 51712       // end 68608
#define WREGION  68608
#define OFF_SBUF WREGION     // per-wave bounce: hi[16][40] + lo[16][40]
#define SB_WAVE  1280
#define LDS_HALVES (OFF_SBUF + WPB*SB_WAVE)   // 78848 halves = 157696 B
static_assert(LDS_HALVES * 2 <= 160*1024, "LDS overflow");

struct fp16p { f16x8 h, l; };
struct h2 { _Float16 h, l; };
struct acc2 { f32x4 m, l; };

__device__ __forceinline__ f32x4 MFMA(f16x8 a, f16x8 b, f32x4 c) {
  return __builtin_amdgcn_mfma_f32_16x16x32_f16(a, b, c, 0, 0, 0);
}

// full K=64 GEMM tile with split planes; weight-lo contribution kept in a
// separate accumulator (weights' lo plane is pre-scaled by LSCALE).
__device__ __forceinline__ void gemm2(const fp16p& A0, const fp16p& B0,
                                      const fp16p& A1, const fp16p& B1, acc2& c) {
  c.m = MFMA(A0.h, B0.h, c.m);
  c.m = MFMA(A0.l, B0.h, c.m);
  c.l = MFMA(A0.h, B0.l, c.l);
  c.m = MFMA(A1.h, B1.h, c.m);
  c.m = MFMA(A1.l, B1.h, c.m);
  c.l = MFMA(A1.h, B1.l, c.l);
}
__device__ __forceinline__ f32x4 fin(const acc2& c) { return c.m + c.l * INV_LSCALE; }

// B fragment pair: lane holds B[k=ks*32+(lane>>4)*8+j][n=nt*16+(lane&15)]
__device__ __forceinline__ fp16p bfragp(const _Float16* w, int RS, int LO,
                                        int nt, int ks, int lane) {
  const _Float16* base = w + (nt*16 + (lane & 15))*RS + ks*32 + (lane >> 4)*8;
  fp16p r;
  r.h = *(const f16x8*)base;
  r.l = *(const f16x8*)(base + LO);
  return r;
}

__device__ __forceinline__ h2 split1(float v) {
  h2 r;
  r.h = (_Float16)v;
  r.l = (_Float16)(v - (float)r.h);
  return r;
}

__device__ __forceinline__ fp16p split8(const float* p, float s) {
  f32x4 a = *(const f32x4*)p, b = *(const f32x4*)(p + 4);
  fp16p r;
#pragma unroll
  for (int i = 0; i < 4; ++i) {
    h2 t0 = split1(a[i]*s);
    h2 t1 = split1(b[i]*s);
    r.h[i]   = t0.h; r.l[i]   = t0.l;
    r.h[4+i] = t1.h; r.l[4+i] = t1.l;
  }
  return r;
}

__device__ __forceinline__ void load24(const float* p, float* vv) {
#pragma unroll
  for (int i = 0; i < 6; ++i) {
    f32x4 t = *(const f32x4*)(p + 4*i);
    vv[4*i+0] = t[0]; vv[4*i+1] = t[1]; vv[4*i+2] = t[2]; vv[4*i+3] = t[3];
  }
}

// W is [K][NN] row-major in global; store hi/lo n-major, scale folded, lo×LSCALE
template<int K, int NN, int RS, int LO>
__device__ __forceinline__ void stage_ws(const float* __restrict__ W, _Float16* dst,
                                         float scale, int tid) {
#pragma unroll 1
  for (int idx = tid; idx < K*NN; idx += TPB) {
    int u = idx / NN;
    int n = idx - u*NN;
    float v = W[idx] * scale;
    _Float16 h = (_Float16)v;
    float res = (v - (float)h) * LSCALE;     // exact pow2 scale of exact residual
    dst[n*RS + u]      = h;
    dst[n*RS + LO + u] = (_Float16)res;
  }
}

#define LGKM0() asm volatile("s_waitcnt lgkmcnt(0)" ::: "memory")

__global__ __launch_bounds__(TPB, 2) void tp_fused(
    const float* __restrict__ x,    const float* __restrict__ y,
    const float* __restrict__ sc,
    const float* __restrict__ Wtp1, const float* __restrict__ Wtp2,
    const float* __restrict__ Wtp3, const float* __restrict__ Wtp4,
    const float* __restrict__ Wfc1, const float* __restrict__ Wfc2,
    const float* __restrict__ Wfc3, const float* __restrict__ Wlin0,
    const float* __restrict__ Wlin1, float* __restrict__ out)
{
  __shared__ _Float16 lds[LDS_HALVES];
  const int tid = threadIdx.x;

  const float INV8   = 0.125f;
  const float INVS3  = 0.57735026918962576f;
  const float INVSMD = 0.08838834764831845f;

  // ---------- phase 1 staging: MLP weights ----------
  stage_ws<64, 64, RS64, LO64>(Wfc1, lds + OFF_FC1, INV8, tid);
  stage_ws<64, 64, RS64, LO64>(Wfc2, lds + OFF_FC2, INV8, tid);
  stage_ws<64, 256,RS64, LO64>(Wfc3, lds + OFF_FC3, INV8, tid);
  __syncthreads();

  const int lane = tid & 63;
  const int wave = tid >> 6;
  const int tile = blockIdx.x * WPB + wave;
  const bool active = (tile < NTILES);
  const int r0   = (active ? tile : 0) * 16;
  const int arow = lane & 15;
  const int kgrp = lane >> 4;
  const int rowg = r0 + arow;
  _Float16* swbh = lds + OFF_SBUF + wave*SB_WAVE;
  _Float16* swbl = swbh + 640;

  // ---- y broadcast ----
  const float yv = y[r0*4 + lane];
  const float y0A  = __shfl(yv, arow*4 + 0);
  const float y1A0 = __shfl(yv, arow*4 + 1);
  const float y1A1 = __shfl(yv, arow*4 + 2);
  const float y1A2 = __shfl(yv, arow*4 + 3);
  float y1D[3][4];
#pragma unroll
  for (int m = 0; m < 3; ++m)
#pragma unroll
    for (int r = 0; r < 4; ++r)
      y1D[m][r] = __shfl(yv, (kgrp*4 + r)*4 + 1 + m);

  // bounce a 16x64 fp32 D-tile (4 f32x4 col-tiles) into A-frag pairs (opt. silu)
  auto bounce = [&](const f32x4* zz, bool do_silu, fp16p& A0, fp16p& A1) {
#pragma unroll
    for (int c = 0; c < 2; ++c) {
      LGKM0();   // WAR: prior reads of this region retired
#pragma unroll
      for (int ntl = 0; ntl < 2; ++ntl)
#pragma unroll
        for (int r = 0; r < 4; ++r) {
          float v = zz[c*2 + ntl][r];
          if (do_silu) v = v / (1.f + __expf(-v));
          h2 t = split1(v);
          int o = (kgrp*4 + r)*40 + ntl*16 + arow;
          swbh[o] = t.h;
          swbl[o] = t.l;
        }
      LGKM0();   // writes visible
      fp16p& A = c ? A1 : A0;
      A.h = *(const f16x8*)(swbh + arow*40 + kgrp*8);
      A.l = *(const f16x8*)(swbl + arow*40 + kgrp*8);
    }
  };

  // ================= MLP =================
  const float* scp = sc + rowg*64;
  fp16p A0 = split8(scp + kgrp*8, 1.f);
  fp16p A1 = split8(scp + 32 + kgrp*8, 1.f);

  f32x4 z[4];
#pragma unroll
  for (int nt = 0; nt < 4; ++nt) {
    acc2 c{};
    gemm2(A0, bfragp(lds + OFF_FC1, RS64, LO64, nt, 0, lane),
          A1, bfragp(lds + OFF_FC1, RS64, LO64, nt, 1, lane), c);
    z[nt] = fin(c);
  }
  bounce(z, true, A0, A1);

  f32x4 z2[4];
#pragma unroll
  for (int nt = 0; nt < 4; ++nt) {
    acc2 c{};
    gemm2(A0, bfragp(lds + OFF_FC2, RS64, LO64, nt, 0, lane),
          A1, bfragp(lds + OFF_FC2, RS64, LO64, nt, 1, lane), c);
    z2[nt] = fin(c);
  }
  bounce(z2, true, A0, A1);

  f32x4 w[16];   // w[0..7]=w0 cols 0..127, w[8..15]=w1 cols 128..255
#pragma unroll
  for (int nt = 0; nt < 16; ++nt) {
    acc2 c{};
    gemm2(A0, bfragp(lds + OFF_FC3, RS64, LO64, nt, 0, lane),
          A1, bfragp(lds + OFF_FC3, RS64, LO64, nt, 1, lane), c);
    w[nt] = fin(c);
  }

  // ---------- phase 2 staging: TP + LIN weights (reuse region) ----------
  __syncthreads();   // everyone done reading MLP weights
  stage_ws<64, 64, RS64, LO64>(Wtp1, lds + OFF_TP1, INV8,       tid);
  stage_ws<64, 64, RS64, LO64>(Wtp2, lds + OFF_TP2, INV8,       tid);
  stage_ws<64, 64, RS64, LO64>(Wtp3, lds + OFF_TP3, INV8,       tid);
  stage_ws<64, 64, RS64, LO64>(Wtp4, lds + OFF_TP4, INV8*INVS3, tid);
  stage_ws<128,64, RS128,LO128>(Wlin0, lds + OFF_LIN0, INVSMD,  tid);
  stage_ws<128,64, RS128,LO128>(Wlin1, lds + OFF_LIN1, INVSMD,  tid);
  __syncthreads();

  // ================= x-dependent GEMMs =================
  const float* xr = x + rowg*256;
  fp16p X0 = split8(xr + kgrp*8, 1.f);          // x0, k 0..31
  fp16p X1 = split8(xr + 32 + kgrp*8, 1.f);     // x0, k 32..63
  fp16p Aa0 = split8(xr + kgrp*8, y0A);         // x0*y0
  fp16p Aa1 = split8(xr + 32 + kgrp*8, y0A);

  f32x4 t4[4];   // t = x0 @ Wtp2/8
  f32x4 m0[8];   // mid0 = [mid0a | mid0b]
#pragma unroll
  for (int nt = 0; nt < 4; ++nt) {
    acc2 ct{}, cm{};
    gemm2(X0,  bfragp(lds + OFF_TP2, RS64, LO64, nt, 0, lane),
          X1,  bfragp(lds + OFF_TP2, RS64, LO64, nt, 1, lane), ct);
    gemm2(Aa0, bfragp(lds + OFF_TP1, RS64, LO64, nt, 0, lane),
          Aa1, bfragp(lds + OFF_TP1, RS64, LO64, nt, 1, lane), cm);
    t4[nt] = fin(ct);
    m0[nt] = fin(cm);
  }

  // a1[u] = sum_m x1[u][m]*y1[m]
  fp16p B40, B41;
  {
    float vv[24];
    load24(xr + 64 + 3*(kgrp*8), vv);
#pragma unroll
    for (int j = 0; j < 8; ++j) {
      h2 t = split1(vv[3*j]*y1A0 + vv[3*j+1]*y1A1 + vv[3*j+2]*y1A2);
      B40.h[j] = t.h; B40.l[j] = t.l;
    }
    load24(xr + 64 + 3*(32 + kgrp*8), vv);
#pragma unroll
    for (int j = 0; j < 8; ++j) {
      h2 t = split1(vv[3*j]*y1A0 + vv[3*j+1]*y1A1 + vv[3*j+2]*y1A2);
      B41.h[j] = t.h; B41.l[j] = t.l;
    }
  }
#pragma unroll
  for (int nt = 0; nt < 4; ++nt) {
    acc2 c{};
    gemm2(B40, bfragp(lds + OFF_TP4, RS64, LO64, nt, 0, lane),
          B41, bfragp(lds + OFF_TP4, RS64, LO64, nt, 1, lane), c);
    m0[4+nt] = fin(c);
  }

  // ---- out0 = (mid0*w0) @ Wlin0 ----
  acc2 o0c[4] = {};
#pragma unroll
  for (int half = 0; half < 2; ++half) {
    f32x4 s[4];
#pragma unroll
    for (int nt = 0; nt < 4; ++nt)
#pragma unroll
      for (int r = 0; r < 4; ++r)
        s[nt][r] = m0[half*4 + nt][r] * w[half*4 + nt][r];
    fp16p S0, S1;
    bounce(s, false, S0, S1);
#pragma unroll
    for (int nt = 0; nt < 4; ++nt)
      gemm2(S0, bfragp(lds + OFF_LIN0, RS128, LO128, nt, half*2+0, lane),
            S1, bfragp(lds + OFF_LIN0, RS128, LO128, nt, half*2+1, lane), o0c[nt]);
  }
  if (active) {
#pragma unroll
    for (int nt = 0; nt < 4; ++nt) {
      f32x4 v = fin(o0c[nt]);
#pragma unroll
      for (int r = 0; r < 4; ++r)
        out[(r0 + kgrp*4 + r)*256 + nt*16 + arow] = v[r];
    }
  }

  // ---- per-m: mid1b = (x1_m*y0)@Wtp3; out1_m = (mid1_m*w1)@Wlin1 ----
#pragma unroll 1
  for (int m = 0; m < 3; ++m) {
    fp16p C0, C1;
    {
      float vv[24];
      load24(xr + 64 + 3*(kgrp*8), vv);
#pragma unroll
      for (int j = 0; j < 8; ++j) {
        h2 t = split1(vv[3*j + m] * y0A);
        C0.h[j] = t.h; C0.l[j] = t.l;
      }
      load24(xr + 64 + 3*(32 + kgrp*8), vv);
#pragma unroll
      for (int j = 0; j < 8; ++j) {
        h2 t = split1(vv[3*j + m] * y0A);
        C1.h[j] = t.h; C1.l[j] = t.l;
      }
    }
    f32x4 mb[4];
#pragma unroll
    for (int nt = 0; nt < 4; ++nt) {
      acc2 c{};
      gemm2(C0, bfragp(lds + OFF_TP3, RS64, LO64, nt, 0, lane),
            C1, bfragp(lds + OFF_TP3, RS64, LO64, nt, 1, lane), c);
      mb[nt] = fin(c);
    }

    acc2 o1c[4] = {};
    // half 0: mid1a = t*y1[m], gate w1[0..63] = w[8..11], lin1 k 0..63
    {
      f32x4 s[4];
#pragma unroll
      for (int nt = 0; nt < 4; ++nt)
#pragma unroll
        for (int r = 0; r < 4; ++r)
          s[nt][r] = t4[nt][r] * y1D[m][r] * w[8 + nt][r];
      fp16p S0, S1;
      bounce(s, false, S0, S1);
#pragma unroll
      for (int nt = 0; nt < 4; ++nt)
        gemm2(S0, bfragp(lds + OFF_LIN1, RS128, LO128, nt, 0, lane),
              S1, bfragp(lds + OFF_LIN1, RS128, LO128, nt, 1, lane), o1c[nt]);
    }
    // half 1: mid1b, gate w1[64..127] = w[12..15], lin1 k 64..127
    {
      f32x4 s[4];
#pragma unroll
      for (int nt = 0; nt < 4; ++nt)
#pragma unroll
        for (int r = 0; r < 4; ++r)
          s[nt][r] = mb[nt][r] * w[12 + nt][r];
      fp16p S0, S1;
      bounce(s, false, S0, S1);
#pragma unroll
      for (int nt = 0; nt < 4; ++nt)
        gemm2(S0, bfragp(lds + OFF_LIN1, RS128, LO128, nt, 2, lane),
              S1, bfragp(lds + OFF_LIN1, RS128, LO128, nt, 3, lane), o1c[nt]);
    }
    if (active) {
#pragma unroll
      for (int nt = 0; nt < 4; ++nt) {
        f32x4 v = fin(o1c[nt]);
#pragma unroll
        for (int r = 0; r < 4; ++r)
          out[(r0 + kgrp*4 + r)*256 + 64 + (nt*16 + arow)*3 + m] = v[r];
      }
    }
  }
}

extern "C" void kernel_launch(void* const* d_in, const int* in_sizes, int n_in,
                              void* d_out, int out_size, void* d_ws, size_t ws_size,
                              hipStream_t stream) {
  (void)in_sizes; (void)n_in; (void)out_size; (void)d_ws; (void)ws_size;
  tp_fused<<<NBLK, TPB, 0, stream>>>(
      (const float*)d_in[0],  (const float*)d_in[1],  (const float*)d_in[2],
      (const float*)d_in[3],  (const float*)d_in[4],  (const float*)d_in[5],
      (const float*)d_in[6],  (const float*)d_in[7],  (const float*)d_in[8],
      (const float*)d_in[9],  (const float*)d_in[10], (const float*)d_in[11],
      (float*)d_out);
}

// Round 8
// 460.682 us; speedup vs baseline: 1.0667x; 1.0667x over previous
//
#include <hip/hip_runtime.h>

typedef _Float16 f16x8 __attribute__((ext_vector_type(8)));
typedef float    f32x4 __attribute__((ext_vector_type(4)));

#define NROWS  300000
#define NTILES (NROWS/16)      // 18750
#define WPB    8
#define TPB    512
#define NBLK   ((NTILES + WPB - 1) / WPB)  // 2344

// weight-lo plane pre-scaled by 2^11 (stays out of f16-denormal range)
#define LSCALE     2048.0f
#define INV_LSCALE 4.8828125e-4f   // 2^-11 exact

// ---- LDS layout (halves). Weights n-major, hi plane col 0, lo plane at LO.
#define RS64   136
#define LO64   72
#define RS128  264
#define LO128  136
// phase 1
#define OFF_FC1 0
#define OFF_FC2 8704
#define OFF_FC3 17408
// phase 2 (same region, re-staged after barrier)
#define OFF_TP1 0
#define OFF_TP2 8704
#define OFF_TP3 17408
#define OFF_TP4 26112
#define OFF_LIN0 34816
#define OFF_LIN1 51712
#define WREGION  68608
#define OFF_SBUF WREGION     // per-wave bounce: hi[16][40] + lo[16][40]
#define SB_WAVE  1280
#define LDS_HALVES (OFF_SBUF + WPB*SB_WAVE)   // 78848 halves = 157696 B
static_assert(LDS_HALVES * 2 <= 160*1024, "LDS overflow");

struct fp16p { f16x8 h, l; };
struct h2 { _Float16 h, l; };
struct acc2 { f32x4 m, l; };

__device__ __forceinline__ f32x4 MFMA(f16x8 a, f16x8 b, f32x4 c) {
  return __builtin_amdgcn_mfma_f32_16x16x32_f16(a, b, c, 0, 0, 0);
}

// emulated-fp32 K=64 GEMM tile: hi*hi + lo*hi in main acc, hi*lo (x2048) in lo acc
__device__ __forceinline__ void gemm2(const fp16p& A0, const fp16p& B0,
                                      const fp16p& A1, const fp16p& B1, acc2& c) {
  c.m = MFMA(A0.h, B0.h, c.m);
  c.m = MFMA(A0.l, B0.h, c.m);
  c.l = MFMA(A0.h, B0.l, c.l);
  c.m = MFMA(A1.h, B1.h, c.m);
  c.m = MFMA(A1.l, B1.h, c.m);
  c.l = MFMA(A1.h, B1.l, c.l);
}
__device__ __forceinline__ f32x4 fin(const acc2& c) { return c.m + c.l * INV_LSCALE; }

__device__ __forceinline__ fp16p bfragp(const _Float16* w, int RS, int LO,
                                        int nt, int ks, int lane) {
  const _Float16* base = w + (nt*16 + (lane & 15))*RS + ks*32 + (lane >> 4)*8;
  fp16p r;
  r.h = *(const f16x8*)base;
  r.l = *(const f16x8*)(base + LO);
  return r;
}

__device__ __forceinline__ h2 split1(float v) {
  h2 r;
  r.h = (_Float16)v;
  r.l = (_Float16)(v - (float)r.h);
  return r;
}

__device__ __forceinline__ fp16p split8(const float* p, float s) {
  f32x4 a = *(const f32x4*)p, b = *(const f32x4*)(p + 4);
  fp16p r;
#pragma unroll
  for (int i = 0; i < 4; ++i) {
    h2 t0 = split1(a[i]*s);
    h2 t1 = split1(b[i]*s);
    r.h[i]   = t0.h; r.l[i]   = t0.l;
    r.h[4+i] = t1.h; r.l[4+i] = t1.l;
  }
  return r;
}

__device__ __forceinline__ void load24(const float* p, float* vv) {
#pragma unroll
  for (int i = 0; i < 6; ++i) {
    f32x4 t = *(const f32x4*)(p + 4*i);
    vv[4*i+0] = t[0]; vv[4*i+1] = t[1]; vv[4*i+2] = t[2]; vv[4*i+3] = t[3];
  }
}

template<int K, int NN, int RS, int LO>
__device__ __forceinline__ void stage_ws(const float* __restrict__ W, _Float16* dst,
                                         float scale, int tid) {
#pragma unroll 1
  for (int idx = tid; idx < K*NN; idx += TPB) {
    int u = idx / NN;
    int n = idx - u*NN;
    float v = W[idx] * scale;
    _Float16 h = (_Float16)v;
    float res = (v - (float)h) * LSCALE;
    dst[n*RS + u]      = h;
    dst[n*RS + LO + u] = (_Float16)res;
  }
}

#define LGKM0() asm volatile("s_waitcnt lgkmcnt(0)" ::: "memory")

__global__ __launch_bounds__(TPB, 2) void tp_fused(
    const float* __restrict__ x,    const float* __restrict__ y,
    const float* __restrict__ sc,
    const float* __restrict__ Wtp1, const float* __restrict__ Wtp2,
    const float* __restrict__ Wtp3, const float* __restrict__ Wtp4,
    const float* __restrict__ Wfc1, const float* __restrict__ Wfc2,
    const float* __restrict__ Wfc3, const float* __restrict__ Wlin0,
    const float* __restrict__ Wlin1, float* __restrict__ out)
{
  __shared__ _Float16 lds[LDS_HALVES];
  const int tid = threadIdx.x;

  const float INV8   = 0.125f;
  const float INVS3  = 0.57735026918962576f;
  const float INVSMD = 0.08838834764831845f;

  // ---------- phase 1 staging ----------
  stage_ws<64, 64, RS64, LO64>(Wfc1, lds + OFF_FC1, INV8, tid);
  stage_ws<64, 64, RS64, LO64>(Wfc2, lds + OFF_FC2, INV8, tid);
  stage_ws<64, 256,RS64, LO64>(Wfc3, lds + OFF_FC3, INV8, tid);
  __syncthreads();

  const int lane = tid & 63;
  const int wave = tid >> 6;
  const int tile = blockIdx.x * WPB + wave;
  const bool active = (tile < NTILES);
  const int r0   = (active ? tile : 0) * 16;
  const int arow = lane & 15;
  const int kgrp = lane >> 4;
  const int rowg = r0 + arow;
  _Float16* swbh = lds + OFF_SBUF + wave*SB_WAVE;
  _Float16* swbl = swbh + 640;

  // ---- y broadcast ----
  const float yv = y[r0*4 + lane];
  const float y0A  = __shfl(yv, arow*4 + 0);
  const float y1A0 = __shfl(yv, arow*4 + 1);
  const float y1A1 = __shfl(yv, arow*4 + 2);
  const float y1A2 = __shfl(yv, arow*4 + 3);
  float y1D[3][4];
#pragma unroll
  for (int m = 0; m < 3; ++m)
#pragma unroll
    for (int r = 0; r < 4; ++r)
      y1D[m][r] = __shfl(yv, (kgrp*4 + r)*4 + 1 + m);

  // bounce a 16x64 fp32 D-tile (4 f32x4 col-tiles) into A-frag pairs (opt. silu)
  auto bounce = [&](const f32x4* zz, bool do_silu, fp16p& A0, fp16p& A1) {
#pragma unroll
    for (int c = 0; c < 2; ++c) {
      LGKM0();   // WAR: prior reads of this region retired
#pragma unroll
      for (int ntl = 0; ntl < 2; ++ntl)
#pragma unroll
        for (int r = 0; r < 4; ++r) {
          float v = zz[c*2 + ntl][r];
          if (do_silu) v = v / (1.f + __expf(-v));
          h2 t = split1(v);
          int o = (kgrp*4 + r)*40 + ntl*16 + arow;
          swbh[o] = t.h;
          swbl[o] = t.l;
        }
      LGKM0();   // writes visible
      fp16p& A = c ? A1 : A0;
      A.h = *(const f16x8*)(swbh + arow*40 + kgrp*8);
      A.l = *(const f16x8*)(swbl + arow*40 + kgrp*8);
    }
  };

  // ================= MLP =================
  const float* scp = sc + rowg*64;
  fp16p A0 = split8(scp + kgrp*8, 1.f);
  fp16p A1 = split8(scp + 32 + kgrp*8, 1.f);

  f32x4 z[4];
#pragma unroll
  for (int nt = 0; nt < 4; ++nt) {
    acc2 c{};
    gemm2(A0, bfragp(lds + OFF_FC1, RS64, LO64, nt, 0, lane),
          A1, bfragp(lds + OFF_FC1, RS64, LO64, nt, 1, lane), c);
    z[nt] = fin(c);
  }
  bounce(z, true, A0, A1);

  f32x4 z2[4];
#pragma unroll
  for (int nt = 0; nt < 4; ++nt) {
    acc2 c{};
    gemm2(A0, bfragp(lds + OFF_FC2, RS64, LO64, nt, 0, lane),
          A1, bfragp(lds + OFF_FC2, RS64, LO64, nt, 1, lane), c);
    z2[nt] = fin(c);
  }
  bounce(z2, true, A0, A1);

  f32x4 w[16];   // w[0..7]=w0 cols 0..127, w[8..15]=w1 cols 128..255
#pragma unroll
  for (int nt = 0; nt < 16; ++nt) {
    acc2 c{};
    gemm2(A0, bfragp(lds + OFF_FC3, RS64, LO64, nt, 0, lane),
          A1, bfragp(lds + OFF_FC3, RS64, LO64, nt, 1, lane), c);
    w[nt] = fin(c);
  }

  // ---------- phase 2 staging ----------
  __syncthreads();   // everyone done reading MLP weights
  stage_ws<64, 64, RS64, LO64>(Wtp1, lds + OFF_TP1, INV8,       tid);
  stage_ws<64, 64, RS64, LO64>(Wtp2, lds + OFF_TP2, INV8,       tid);
  stage_ws<64, 64, RS64, LO64>(Wtp3, lds + OFF_TP3, INV8,       tid);
  stage_ws<64, 64, RS64, LO64>(Wtp4, lds + OFF_TP4, INV8*INVS3, tid);
  stage_ws<128,64, RS128,LO128>(Wlin0, lds + OFF_LIN0, INVSMD,  tid);
  stage_ws<128,64, RS128,LO128>(Wlin1, lds + OFF_LIN1, INVSMD,  tid);
  __syncthreads();

  // ================= x-dependent GEMMs =================
  const float* xr = x + rowg*256;
  fp16p X0 = split8(xr + kgrp*8, 1.f);          // x0, k 0..31
  fp16p X1 = split8(xr + 32 + kgrp*8, 1.f);     // x0, k 32..63
  fp16p Aa0 = split8(xr + kgrp*8, y0A);         // x0*y0
  fp16p Aa1 = split8(xr + 32 + kgrp*8, y0A);

  f32x4 t4[4];   // t = x0 @ Wtp2/8
  f32x4 m0[8];   // mid0 = [mid0a | mid0b]
#pragma unroll
  for (int nt = 0; nt < 4; ++nt) {
    acc2 ct{}, cm{};
    gemm2(X0,  bfragp(lds + OFF_TP2, RS64, LO64, nt, 0, lane),
          X1,  bfragp(lds + OFF_TP2, RS64, LO64, nt, 1, lane), ct);
    gemm2(Aa0, bfragp(lds + OFF_TP1, RS64, LO64, nt, 0, lane),
          Aa1, bfragp(lds + OFF_TP1, RS64, LO64, nt, 1, lane), cm);
    t4[nt] = fin(ct);
    m0[nt] = fin(cm);
  }

  // a1[u] = sum_m x1[u][m]*y1[m]
  fp16p B40, B41;
  {
    float vv[24];
    load24(xr + 64 + 3*(kgrp*8), vv);
#pragma unroll
    for (int j = 0; j < 8; ++j) {
      h2 t = split1(vv[3*j]*y1A0 + vv[3*j+1]*y1A1 + vv[3*j+2]*y1A2);
      B40.h[j] = t.h; B40.l[j] = t.l;
    }
    load24(xr + 64 + 3*(32 + kgrp*8), vv);
#pragma unroll
    for (int j = 0; j < 8; ++j) {
      h2 t = split1(vv[3*j]*y1A0 + vv[3*j+1]*y1A1 + vv[3*j+2]*y1A2);
      B41.h[j] = t.h; B41.l[j] = t.l;
    }
  }
#pragma unroll
  for (int nt = 0; nt < 4; ++nt) {
    acc2 c{};
    gemm2(B40, bfragp(lds + OFF_TP4, RS64, LO64, nt, 0, lane),
          B41, bfragp(lds + OFF_TP4, RS64, LO64, nt, 1, lane), c);
    m0[4+nt] = fin(c);
  }

  // ---- out0 = (mid0*w0) @ Wlin0 ----
  acc2 o0c[4] = {};
#pragma unroll
  for (int half = 0; half < 2; ++half) {
    f32x4 s[4];
#pragma unroll
    for (int nt = 0; nt < 4; ++nt)
#pragma unroll
      for (int r = 0; r < 4; ++r)
        s[nt][r] = m0[half*4 + nt][r] * w[half*4 + nt][r];
    fp16p S0, S1;
    bounce(s, false, S0, S1);
#pragma unroll
    for (int nt = 0; nt < 4; ++nt)
      gemm2(S0, bfragp(lds + OFF_LIN0, RS128, LO128, nt, half*2+0, lane),
            S1, bfragp(lds + OFF_LIN0, RS128, LO128, nt, half*2+1, lane), o0c[nt]);
  }
  if (active) {
#pragma unroll
    for (int nt = 0; nt < 4; ++nt) {
      f32x4 v = fin(o0c[nt]);
#pragma unroll
      for (int r = 0; r < 4; ++r)
        out[(r0 + kgrp*4 + r)*256 + nt*16 + arow] = v[r];
    }
  }

  // ---- per-m: mid1b = (x1_m*y0)@Wtp3; out1_m = (mid1_m*w1)@Wlin1 ----
  f32x4 o1f[3][4];   // buffered; m-loop fully unrolled -> static indexing
#pragma unroll
  for (int m = 0; m < 3; ++m) {
    fp16p C0, C1;
    {
      float vv[24];
      load24(xr + 64 + 3*(kgrp*8), vv);          // L1-resident reload
#pragma unroll
      for (int j = 0; j < 8; ++j) {
        h2 t = split1(vv[3*j + m] * y0A);
        C0.h[j] = t.h; C0.l[j] = t.l;
      }
      load24(xr + 64 + 3*(32 + kgrp*8), vv);
#pragma unroll
      for (int j = 0; j < 8; ++j) {
        h2 t = split1(vv[3*j + m] * y0A);
        C1.h[j] = t.h; C1.l[j] = t.l;
      }
    }
    f32x4 mb[4];
#pragma unroll
    for (int nt = 0; nt < 4; ++nt) {
      acc2 c{};
      gemm2(C0, bfragp(lds + OFF_TP3, RS64, LO64, nt, 0, lane),
            C1, bfragp(lds + OFF_TP3, RS64, LO64, nt, 1, lane), c);
      mb[nt] = fin(c);
    }

    acc2 o1c[4] = {};
    // half 0: mid1a = t*y1[m], gate w1[0..63] = w[8..11], lin1 k 0..63
    {
      f32x4 s[4];
#pragma unroll
      for (int nt = 0; nt < 4; ++nt)
#pragma unroll
        for (int r = 0; r < 4; ++r)
          s[nt][r] = t4[nt][r] * y1D[m][r] * w[8 + nt][r];
      fp16p S0, S1;
      bounce(s, false, S0, S1);
#pragma unroll
      for (int nt = 0; nt < 4; ++nt)
        gemm2(S0, bfragp(lds + OFF_LIN1, RS128, LO128, nt, 0, lane),
              S1, bfragp(lds + OFF_LIN1, RS128, LO128, nt, 1, lane), o1c[nt]);
    }
    // half 1: mid1b, gate w1[64..127] = w[12..15], lin1 k 64..127
    {
      f32x4 s[4];
#pragma unroll
      for (int nt = 0; nt < 4; ++nt)
#pragma unroll
        for (int r = 0; r < 4; ++r)
          s[nt][r] = mb[nt][r] * w[12 + nt][r];
      fp16p S0, S1;
      bounce(s, false, S0, S1);
#pragma unroll
      for (int nt = 0; nt < 4; ++nt)
        gemm2(S0, bfragp(lds + OFF_LIN1, RS128, LO128, nt, 2, lane),
              S1, bfragp(lds + OFF_LIN1, RS128, LO128, nt, 3, lane), o1c[nt]);
    }
#pragma unroll
    for (int nt = 0; nt < 4; ++nt)
      o1f[m][nt] = fin(o1c[nt]);
  }

  if (active) {
#pragma unroll
    for (int nt = 0; nt < 4; ++nt)
#pragma unroll
      for (int r = 0; r < 4; ++r) {
        float* p = out + (r0 + kgrp*4 + r)*256 + 64 + (nt*16 + arow)*3;
        p[0] = o1f[0][nt][r];
        p[1] = o1f[1][nt][r];
        p[2] = o1f[2][nt][r];
      }
  }
}

extern "C" void kernel_launch(void* const* d_in, const int* in_sizes, int n_in,
                              void* d_out, int out_size, void* d_ws, size_t ws_size,
                              hipStream_t stream) {
  (void)in_sizes; (void)n_in; (void)out_size; (void)d_ws; (void)ws_size;
  tp_fused<<<NBLK, TPB, 0, stream>>>(
      (const float*)d_in[0],  (const float*)d_in[1],  (const float*)d_in[2],
      (const float*)d_in[3],  (const float*)d_in[4],  (const float*)d_in[5],
      (const float*)d_in[6],  (const float*)d_in[7],  (const float*)d_in[8],
      (const float*)d_in[9],  (const float*)d_in[10], (const float*)d_in[11],
      (float*)d_out);
}